// Round 7
// baseline (272.500 us; speedup 1.0000x reference)
//
#include <hip/hip_runtime.h>

#define NB 8
#define NT 30000
#define NL 6
#define NC 32
#define NHID 256

typedef _Float16 f16;
typedef f16 half8 __attribute__((ext_vector_type(8)));
typedef f16 half4v __attribute__((ext_vector_type(4)));
typedef f16 half2v __attribute__((ext_vector_type(2)));
typedef float floatx4 __attribute__((ext_vector_type(4)));

// Row permutation so MFMA D-layout lands in "lane(q) owns channels 8q..8q+7" order.
__device__ __forceinline__ int permrow(int m) {
    return 8 * ((m & 15) >> 2) + 4 * (m >> 4) + (m & 3);
}

__device__ __forceinline__ half2v cvt2(float a, float b) {
    return __builtin_bit_cast(half2v, __builtin_amdgcn_cvt_pkrtz(a, b));
}

// relu + pack two floatx4 -> half8, register-only
__device__ __forceinline__ half8 relupack2(floatx4 a, floatx4 b) {
    half2v p0 = cvt2(fmaxf(a[0], 0.f), fmaxf(a[1], 0.f));
    half2v p1 = cvt2(fmaxf(a[2], 0.f), fmaxf(a[3], 0.f));
    half2v p2 = cvt2(fmaxf(b[0], 0.f), fmaxf(b[1], 0.f));
    half2v p3 = cvt2(fmaxf(b[2], 0.f), fmaxf(b[3], 0.f));
    half4v q0 = __builtin_shufflevector(p0, p1, 0, 1, 2, 3);
    half4v q1 = __builtin_shufflevector(p2, p3, 0, 1, 2, 3);
    return __builtin_shufflevector(q0, q1, 0, 1, 2, 3, 4, 5, 6, 7);
}

// zero-extend half4v -> half8 (hi half zero), register-only
__device__ __forceinline__ half8 zext4(half4v lo) {
    const half4v zh = {};
    return __builtin_shufflevector(lo, zh, 0, 1, 2, 3, 4, 5, 6, 7);
}

// one view, one point: accumulate bilinear sample of this lane's 8 channels
__device__ __forceinline__ void gatherv(const float* __restrict__ base, float x, float y,
                                        floatx4& f0, floatx4& f1) {
    float x0f = floorf(x), x1f = ceilf(x);
    float y0f = floorf(y), y1f = ceilf(y);
    float dxw = x1f - x, dyw = y1f - y;
    int x0 = min(max((int)x0f, 0), 127);
    int x1 = min(max((int)x1f, 0), 127);
    int y0 = min(max((int)y0f, 0), 127);
    int y1 = min(max((int)y1f, 0), 127);
    const floatx4* f11 = (const floatx4*)(base + (size_t)((x0 << 7) + y0) * 32);
    const floatx4* f12 = (const floatx4*)(base + (size_t)((x1 << 7) + y0) * 32);
    const floatx4* f21 = (const floatx4*)(base + (size_t)((x0 << 7) + y1) * 32);
    const floatx4* f22 = (const floatx4*)(base + (size_t)((x1 << 7) + y1) * 32);
    float w11 = dxw * dyw;
    float w12 = (1.f - dxw) * dyw;
    float w21 = dxw * (1.f - dyw);
    float w22 = (1.f - dxw) * (1.f - dyw);
    floatx4 a0 = f11[0], a1 = f11[1];
    floatx4 b0v = f12[0], b1v = f12[1];
    floatx4 c0v = f21[0], c1v = f21[1];
    floatx4 d0v = f22[0], d1v = f22[1];
    f0 += a0 * w11 + b0v * w12 + c0v * w21 + d0v * w22;
    f1 += a1 * w11 + b1v * w12 + c1v * w21 + d1v * w22;
}

// (256, 2): unified arch-VGPR + AGPR cap 256. 3 waves/SIMD (cap 168) spills
// ~340 MB of scratch per dispatch (rounds 3-5). Keep at 2.
__launch_bounds__(256, 2)
__global__ void decoder_kernel(
    const float* __restrict__ p, const float* __restrict__ c, const float* __restrict__ Cm,
    const float* __restrict__ fpw, const float* __restrict__ fpb,
    const float* __restrict__ b0w0, const float* __restrict__ b0b0,
    const float* __restrict__ b0w1, const float* __restrict__ b0b1,
    const float* __restrict__ b0ws, const float* __restrict__ bw0,
    const float* __restrict__ bb0, const float* __restrict__ bw1,
    const float* __restrict__ bb1, const float* __restrict__ fow,
    const float* __restrict__ fob, float* __restrict__ out)
{
    __shared__ __align__(16) f16 s_w0A[32 * 256];   // 16 KB; b128 chunk c -> c ^ (m&7)
    __shared__ __align__(16) f16 s_wA[9 * 32 * 32]; // 18 KB; b128 chunk c -> c ^ ((m>>1)&3)
    __shared__ __align__(16) f16 s_hB[256 * 4];     // 2 KB; hidden {w0,w1,w2,b} rows
    __shared__ __align__(16) f16 s_foldA[32 * 4];   // 256 B; {M0,M1,M2,v+b0b1}
    __shared__ floatx4 s_part[8][32];               // 4 KB; fold partials
    __shared__ __align__(16) float s_b0b0[32], s_fow[32];
    __shared__ __align__(16) float s_bb0f[128], s_bb1f[128];
    __shared__ float s_cam[NL][8];
    __shared__ float s_fob;

    const int tid = threadIdx.x;
    const int b = blockIdx.y;

    // ---- staging ----
    {   // s_w0A: row m = tid>>3, seg = tid&7 -> 4 b128 chunks, slot = chunk ^ (m&7)
        int m = tid >> 3, seg = tid & 7;
        const float* src = b0w0 + permrow(m) * 256 + seg * 32;
        f16* dst = s_w0A + m * 256;
        int sw = m & 7;
        #pragma unroll
        for (int ci = 0; ci < 4; ci++) {
            int cidx = seg * 4 + ci;
            floatx4 f0 = *(const floatx4*)(src + ci * 8);
            floatx4 f1 = *(const floatx4*)(src + ci * 8 + 4);
            half2v h0 = cvt2(f0[0], f0[1]), h1 = cvt2(f0[2], f0[3]);
            half2v h2 = cvt2(f1[0], f1[1]), h3 = cvt2(f1[2], f1[3]);
            half4v q0 = __builtin_shufflevector(h0, h1, 0, 1, 2, 3);
            half4v q1 = __builtin_shufflevector(h2, h3, 0, 1, 2, 3);
            half8 h = __builtin_shufflevector(q0, q1, 0, 1, 2, 3, 4, 5, 6, 7);
            *(half8*)(dst + ((cidx ^ sw) << 3)) = h;
        }
    }
    // s_wA: 9 mats x 32 rows; 4 b128 chunks per row at slot c ^ ((m>>1)&3)
    for (int r = tid; r < 288; r += 256) {
        int mi = r >> 5, m = r & 31;
        int pm = permrow(m);
        const float* src;
        if (mi == 0) src = b0w1 + pm * 32;
        else {
            int mat = mi - 1, bi = mat >> 1;
            src = ((mat & 1) ? bw1 : bw0) + (bi * 32 + pm) * 32;
        }
        f16* dst = s_wA + mi * 1024 + m * 32;
        int sw = (m >> 1) & 3;
        #pragma unroll
        for (int ci = 0; ci < 4; ci++) {
            floatx4 f0 = *(const floatx4*)(src + ci * 8);
            floatx4 f1 = *(const floatx4*)(src + ci * 8 + 4);
            half2v h0 = cvt2(f0[0], f0[1]), h1 = cvt2(f0[2], f0[3]);
            half2v h2 = cvt2(f1[0], f1[1]), h3 = cvt2(f1[2], f1[3]);
            half4v q0 = __builtin_shufflevector(h0, h1, 0, 1, 2, 3);
            half4v q1 = __builtin_shufflevector(h2, h3, 0, 1, 2, 3);
            half8 h = __builtin_shufflevector(q0, q1, 0, 1, 2, 3, 4, 5, 6, 7);
            *(half8*)(dst + ((ci ^ sw) << 3)) = h;
        }
    }
    {   // s_hB: row tid = (cch,m) holds hidden h = cch*32 + permrow(m)
        int cch = tid >> 5, m = tid & 31;
        int h = cch * 32 + permrow(m);
        half2v a = cvt2(fpw[h * 3 + 0], fpw[h * 3 + 1]);
        half2v bq = cvt2(fpw[h * 3 + 2], fpb[h]);
        *(half4v*)(s_hB + tid * 4) = __builtin_shufflevector(a, bq, 0, 1, 2, 3);
    }
    {   // fold partials: channel i = tid&31, k-slice kc = tid>>5
        int i = tid & 31, kc = tid >> 5;
        const float* wrow = b0ws + i * 256 + kc * 32;
        const float* pw = fpw + kc * 96;
        const float* pb = fpb + kc * 32;
        floatx4 acc = {};
        #pragma unroll 8
        for (int k = 0; k < 32; k++) {
            float w = wrow[k];
            acc[0] = fmaf(w, pw[k * 3 + 0], acc[0]);
            acc[1] = fmaf(w, pw[k * 3 + 1], acc[1]);
            acc[2] = fmaf(w, pw[k * 3 + 2], acc[2]);
            acc[3] = fmaf(w, pb[k], acc[3]);
        }
        s_part[kc][i] = acc;
    }
    if (tid < 32) {
        s_b0b0[tid] = b0b0[tid];
        s_fow[tid]  = fow[tid];
    }
    if (tid >= 64 && tid < 192) {
        int j = tid - 64;
        s_bb0f[j] = bb0[j];
        s_bb1f[j] = bb1[j];
    }
    if (tid == 0) s_fob = fob[0];
    if (tid >= 192 && tid < 192 + NL) {
        int l = tid - 192;
        const float* cm = Cm + ((size_t)b * NL + l) * 12;
        float denom = cm[9] + 0.05f;
        float s = 63.5f / (0.55f * denom);
        s_cam[l][0] = cm[0] * s; s_cam[l][1] = cm[1] * s; s_cam[l][2] = cm[2] * s;
        s_cam[l][3] = cm[3] * s; s_cam[l][4] = cm[4] * s; s_cam[l][5] = cm[5] * s;
    }
    __syncthreads();
    if (tid < 32) {   // fold reduce -> s_foldA (row m holds channel permrow(m))
        int pm = permrow(tid);
        floatx4 s = s_part[0][pm];
        #pragma unroll
        for (int j = 1; j < 8; j++) s += s_part[j][pm];
        half2v a = cvt2(s[0], s[1]);
        half2v bq = cvt2(s[2], s[3] + b0b1[pm]);
        *(half4v*)(s_foldA + tid * 4) = __builtin_shufflevector(a, bq, 0, 1, 2, 3);
    }
    __syncthreads();

    const int lane = tid & 63;
    const int wv = tid >> 6;
    const int q = lane >> 4;
    const int i16 = lane & 15;
    const int sw0 = i16 & 7;

    // group-invariant LDS bases/offsets (single-b128 A-frag reads everywhere)
    const f16* w0r0 = s_w0A + i16 * 256;
    const f16* w0r1 = s_w0A + (16 + i16) * 256;
    const int qsw = (q ^ ((i16 >> 1) & 3)) << 3;
    const int soff0 = i16 * 32 + qsw;
    const int soff1 = (16 + i16) * 32 + qsw;
    const f16* hB0 = s_hB + i16 * 4;
    const f16* hB1 = s_hB + (16 + i16) * 4;
    const float* cq = c + (((size_t)b * NL) << 19) + q * 8;

    const half8 fA0 = zext4(*(const half4v*)(s_foldA + i16 * 4));
    const half8 fA1 = zext4(*(const half4v*)(s_foldA + (16 + i16) * 4));
    const floatx4 fw0 = *(const floatx4*)&s_fow[q * 8];
    const floatx4 fw1 = *(const floatx4*)&s_fow[q * 8 + 4];
    const floatx4 b00a = *(const floatx4*)&s_b0b0[q * 8];
    const floatx4 b00b = *(const floatx4*)&s_b0b0[q * 8 + 4];

    // ---- two point-groups per wave, interleaved (shared A-frag reads) ----
    const int ta = blockIdx.x * 128 + wv * 16 + i16;
    const int tb = ta + 64;
    const int tca = min(ta, NT - 1), tcb = min(tb, NT - 1);
    const float* ppa = p + ((size_t)b * NT + tca) * 3;
    const float* ppb = p + ((size_t)b * NT + tcb) * 3;
    float pxa = ppa[0], pya = ppa[1], pza = ppa[2];
    float pxb = ppb[0], pyb = ppb[1], pzb = ppb[2];

    // ---- bilinear multi-view gather, both points ----
    floatx4 feA0 = {}, feA1 = {}, feB0 = {}, feB1 = {};
    #pragma unroll 2
    for (int l = 0; l < NL; l++) {
        float c0 = s_cam[l][0], c1 = s_cam[l][1], c2 = s_cam[l][2];
        float c3 = s_cam[l][3], c4 = s_cam[l][4], c5 = s_cam[l][5];
        const float* base = cq + ((size_t)l << 19);
        float xa = c0 * pxa + c1 * pya + c2 * pza + 63.5f;
        float ya = c3 * pxa + c4 * pya + c5 * pza + 63.5f;
        float xb = c0 * pxb + c1 * pyb + c2 * pzb + 63.5f;
        float yb = c3 * pxb + c4 * pyb + c5 * pzb + 63.5f;
        gatherv(base, xa, ya, feA0, feA1);
        gatherv(base, xb, yb, feB0, feB1);
    }

    // ---- B operands for K=4 projections (rows 0..3 live on quad 0) ----
    half8 bpa, bpb;
    {
        const half8 zh8 = {};
        half4v la = __builtin_shufflevector(cvt2(pxa, pya), cvt2(pza, 1.0f), 0, 1, 2, 3);
        half4v lb = __builtin_shufflevector(cvt2(pxb, pyb), cvt2(pzb, 1.0f), 0, 1, 2, 3);
        bpa = (q == 0) ? zext4(la) : zh8;
        bpb = (q == 0) ? zext4(lb) : zh8;
    }

    // ---- blk0: hidden layer (MFMA) + 256->32, dual-point ----
    floatx4 accA0 = b00a, accA1 = b00b, accB0 = b00a, accB1 = b00b;
    #pragma unroll 2
    for (int cch = 0; cch < 8; cch++) {
        half8 ha = zext4(*(const half4v*)(hB0 + cch * 128));
        half8 hb = zext4(*(const half4v*)(hB1 + cch * 128));
        floatx4 hz = {};
        floatx4 h0a = __builtin_amdgcn_mfma_f32_16x16x32_f16(ha, bpa, hz, 0, 0, 0);
        floatx4 h1a = __builtin_amdgcn_mfma_f32_16x16x32_f16(hb, bpa, hz, 0, 0, 0);
        floatx4 h0b = __builtin_amdgcn_mfma_f32_16x16x32_f16(ha, bpb, hz, 0, 0, 0);
        floatx4 h1b = __builtin_amdgcn_mfma_f32_16x16x32_f16(hb, bpb, hz, 0, 0, 0);
        half8 bfa = relupack2(h0a, h1a);
        half8 bfb = relupack2(h0b, h1b);
        half8 a0 = *(const half8*)(w0r0 + ((((cch << 2) | q) ^ sw0) << 3));
        half8 a1 = *(const half8*)(w0r1 + ((((cch << 2) | q) ^ sw0) << 3));
        accA0 = __builtin_amdgcn_mfma_f32_16x16x32_f16(a0, bfa, accA0, 0, 0, 0);
        accA1 = __builtin_amdgcn_mfma_f32_16x16x32_f16(a1, bfa, accA1, 0, 0, 0);
        accB0 = __builtin_amdgcn_mfma_f32_16x16x32_f16(a0, bfb, accB0, 0, 0, 0);
        accB1 = __builtin_amdgcn_mfma_f32_16x16x32_f16(a1, bfb, accB1, 0, 0, 0);
    }

    // ---- st = fold(p)+b0b1 (MFMA, C=feat) + W1 @ relu(acc) ----
    floatx4 stA0 = __builtin_amdgcn_mfma_f32_16x16x32_f16(fA0, bpa, feA0, 0, 0, 0);
    floatx4 stA1 = __builtin_amdgcn_mfma_f32_16x16x32_f16(fA1, bpa, feA1, 0, 0, 0);
    floatx4 stB0 = __builtin_amdgcn_mfma_f32_16x16x32_f16(fA0, bpb, feB0, 0, 0, 0);
    floatx4 stB1 = __builtin_amdgcn_mfma_f32_16x16x32_f16(fA1, bpb, feB1, 0, 0, 0);
    {
        half8 bfa = relupack2(accA0, accA1);
        half8 bfb = relupack2(accB0, accB1);
        half8 a0 = *(const half8*)(s_wA + soff0);
        half8 a1 = *(const half8*)(s_wA + soff1);
        stA0 = __builtin_amdgcn_mfma_f32_16x16x32_f16(a0, bfa, stA0, 0, 0, 0);
        stA1 = __builtin_amdgcn_mfma_f32_16x16x32_f16(a1, bfa, stA1, 0, 0, 0);
        stB0 = __builtin_amdgcn_mfma_f32_16x16x32_f16(a0, bfb, stB0, 0, 0, 0);
        stB1 = __builtin_amdgcn_mfma_f32_16x16x32_f16(a1, bfb, stB1, 0, 0, 0);
    }

    // ---- residual blocks, dual-point with shared weight reads ----
    #pragma unroll
    for (int bk = 0; bk < 4; bk++) {
        const f16* w_a = s_wA + (1 + 2 * bk) * 1024;
        const f16* w_b = s_wA + (2 + 2 * bk) * 1024;
        floatx4 hb0 = *(const floatx4*)&s_bb0f[bk * 32 + q * 8];
        floatx4 hb1 = *(const floatx4*)&s_bb0f[bk * 32 + q * 8 + 4];
        floatx4 hA0 = hb0, hA1 = hb1, hB0v = hb0, hB1v = hb1;
        {
            half8 bfa = relupack2(stA0, stA1);
            half8 bfb = relupack2(stB0, stB1);
            half8 a0 = *(const half8*)(w_a + soff0);
            half8 a1 = *(const half8*)(w_a + soff1);
            hA0 = __builtin_amdgcn_mfma_f32_16x16x32_f16(a0, bfa, hA0, 0, 0, 0);
            hA1 = __builtin_amdgcn_mfma_f32_16x16x32_f16(a1, bfa, hA1, 0, 0, 0);
            hB0v = __builtin_amdgcn_mfma_f32_16x16x32_f16(a0, bfb, hB0v, 0, 0, 0);
            hB1v = __builtin_amdgcn_mfma_f32_16x16x32_f16(a1, bfb, hB1v, 0, 0, 0);
        }
        floatx4 db0 = *(const floatx4*)&s_bb1f[bk * 32 + q * 8];
        floatx4 db1 = *(const floatx4*)&s_bb1f[bk * 32 + q * 8 + 4];
        floatx4 dA0 = db0, dA1 = db1, dB0 = db0, dB1 = db1;
        {
            half8 bfa = relupack2(hA0, hA1);
            half8 bfb = relupack2(hB0v, hB1v);
            half8 a0 = *(const half8*)(w_b + soff0);
            half8 a1 = *(const half8*)(w_b + soff1);
            dA0 = __builtin_amdgcn_mfma_f32_16x16x32_f16(a0, bfa, dA0, 0, 0, 0);
            dA1 = __builtin_amdgcn_mfma_f32_16x16x32_f16(a1, bfa, dA1, 0, 0, 0);
            dB0 = __builtin_amdgcn_mfma_f32_16x16x32_f16(a0, bfb, dB0, 0, 0, 0);
            dB1 = __builtin_amdgcn_mfma_f32_16x16x32_f16(a1, bfb, dB1, 0, 0, 0);
        }
        stA0 += dA0 + feA0;
        stA1 += dA1 + feA1;
        stB0 += dB0 + feB0;
        stB1 += dB1 + feB1;
    }

    // ---- head, both points ----
    float oa = 0.f, ob = 0.f;
    #pragma unroll
    for (int r = 0; r < 4; r++) {
        oa += fmaxf(stA0[r], 0.f) * fw0[r] + fmaxf(stA1[r], 0.f) * fw1[r];
        ob += fmaxf(stB0[r], 0.f) * fw0[r] + fmaxf(stB1[r], 0.f) * fw1[r];
    }
    oa += __shfl_xor(oa, 16);
    oa += __shfl_xor(oa, 32);
    ob += __shfl_xor(ob, 16);
    ob += __shfl_xor(ob, 32);
    if (q == 0) {
        if (ta < NT) out[(size_t)b * NT + ta] = oa + s_fob;
        if (tb < NT) out[(size_t)b * NT + tb] = ob + s_fob;
    }
}

extern "C" void kernel_launch(void* const* d_in, const int* in_sizes, int n_in,
                              void* d_out, int out_size, void* d_ws, size_t ws_size,
                              hipStream_t stream) {
    const float* p    = (const float*)d_in[0];
    const float* c    = (const float*)d_in[2];
    const float* Cm   = (const float*)d_in[3];
    const float* fpw  = (const float*)d_in[4];
    const float* fpb  = (const float*)d_in[5];
    const float* b0w0 = (const float*)d_in[6];
    const float* b0b0 = (const float*)d_in[7];
    const float* b0w1 = (const float*)d_in[8];
    const float* b0b1 = (const float*)d_in[9];
    const float* b0ws = (const float*)d_in[10];
    const float* bw0  = (const float*)d_in[11];
    const float* bb0  = (const float*)d_in[12];
    const float* bw1  = (const float*)d_in[13];
    const float* bb1  = (const float*)d_in[14];
    const float* fow  = (const float*)d_in[15];
    const float* fob  = (const float*)d_in[16];

    dim3 grid((NT + 127) / 128, NB);
    decoder_kernel<<<grid, 256, 0, stream>>>(p, c, Cm, fpw, fpb,
                                             b0w0, b0b0, b0w1, b0b1, b0ws,
                                             bw0, bb0, bw1, bb1,
                                             fow, fob, (float*)d_out);
}

// Round 8
// 263.572 us; speedup vs baseline: 1.0339x; 1.0339x over previous
//
#include <hip/hip_runtime.h>

#define NB 8
#define NT 30000
#define NL 6
#define NC 32
#define NHID 256

typedef _Float16 f16;
typedef f16 half8 __attribute__((ext_vector_type(8)));
typedef f16 half4v __attribute__((ext_vector_type(4)));
typedef f16 half2v __attribute__((ext_vector_type(2)));
typedef float floatx4 __attribute__((ext_vector_type(4)));

#define C_ELEMS (25165824ull)  // 8*6*128*128*32

// Row permutation so MFMA D-layout lands in "lane(q) owns channels 8q..8q+7" order.
__device__ __forceinline__ int permrow(int m) {
    return 8 * ((m & 15) >> 2) + 4 * (m >> 4) + (m & 3);
}

__device__ __forceinline__ half2v cvt2(float a, float b) {
    return __builtin_bit_cast(half2v, __builtin_amdgcn_cvt_pkrtz(a, b));
}

// relu + pack two floatx4 -> half8, register-only
__device__ __forceinline__ half8 relupack2(floatx4 a, floatx4 b) {
    half2v p0 = cvt2(fmaxf(a[0], 0.f), fmaxf(a[1], 0.f));
    half2v p1 = cvt2(fmaxf(a[2], 0.f), fmaxf(a[3], 0.f));
    half2v p2 = cvt2(fmaxf(b[0], 0.f), fmaxf(b[1], 0.f));
    half2v p3 = cvt2(fmaxf(b[2], 0.f), fmaxf(b[3], 0.f));
    half4v q0 = __builtin_shufflevector(p0, p1, 0, 1, 2, 3);
    half4v q1 = __builtin_shufflevector(p2, p3, 0, 1, 2, 3);
    return __builtin_shufflevector(q0, q1, 0, 1, 2, 3, 4, 5, 6, 7);
}

__device__ __forceinline__ half8 zext4(half4v lo) {
    const half4v zh = {};
    return __builtin_shufflevector(lo, zh, 0, 1, 2, 3, 4, 5, 6, 7);
}

__device__ __forceinline__ half8 splat8(float w) {
    f16 h = (f16)w;
    half8 v = {h, h, h, h, h, h, h, h};
    return v;
}

__device__ __forceinline__ void corners(float x, float y, int& i11, int& i12,
                                        int& i21, int& i22, float& dxw, float& dyw) {
    float x0f = floorf(x), x1f = ceilf(x);
    float y0f = floorf(y), y1f = ceilf(y);
    dxw = x1f - x; dyw = y1f - y;
    int x0 = min(max((int)x0f, 0), 127);
    int x1 = min(max((int)x1f, 0), 127);
    int y0 = min(max((int)y0f, 0), 127);
    int y1 = min(max((int)y1f, 0), 127);
    i11 = (x0 << 7) + y0; i12 = (x1 << 7) + y0;
    i21 = (x0 << 7) + y1; i22 = (x1 << 7) + y1;
}

// c (f32) -> f16 copy, same layout. Exact-size grid (C_ELEMS/8 threads).
__global__ __launch_bounds__(256) void convert_kernel(const float* __restrict__ c,
                                                      f16* __restrict__ ch) {
    size_t i = ((size_t)blockIdx.x * 256 + threadIdx.x) * 8;
    floatx4 f0 = *(const floatx4*)(c + i);
    floatx4 f1 = *(const floatx4*)(c + i + 4);
    half2v h0 = cvt2(f0[0], f0[1]), h1 = cvt2(f0[2], f0[3]);
    half2v h2 = cvt2(f1[0], f1[1]), h3 = cvt2(f1[2], f1[3]);
    half4v q0 = __builtin_shufflevector(h0, h1, 0, 1, 2, 3);
    half4v q1 = __builtin_shufflevector(h2, h3, 0, 1, 2, 3);
    *(half8*)(ch + i) = __builtin_shufflevector(q0, q1, 0, 1, 2, 3, 4, 5, 6, 7);
}

// (256, 2): unified arch-VGPR + AGPR cap 256. 3 waves/SIMD (cap 168) spills
// ~340 MB of scratch per dispatch (rounds 3-5). Keep at 2.
template <bool F16>
__global__ __launch_bounds__(256, 2) void decoder_kernel(
    const float* __restrict__ p, const float* __restrict__ c, const f16* __restrict__ chalf,
    const float* __restrict__ Cm,
    const float* __restrict__ fpw, const float* __restrict__ fpb,
    const float* __restrict__ b0w0, const float* __restrict__ b0b0,
    const float* __restrict__ b0w1, const float* __restrict__ b0b1,
    const float* __restrict__ b0ws, const float* __restrict__ bw0,
    const float* __restrict__ bb0, const float* __restrict__ bw1,
    const float* __restrict__ bb1, const float* __restrict__ fow,
    const float* __restrict__ fob, float* __restrict__ out)
{
    __shared__ __align__(16) f16 s_w0A[32 * 256];   // 16 KB; b128 chunk c -> c ^ (m&7)
    __shared__ __align__(16) f16 s_wA[9 * 32 * 32]; // 18 KB; b128 chunk c -> c ^ ((m>>1)&3)
    __shared__ __align__(16) f16 s_hB[256 * 4];     // 2 KB; hidden {w0,w1,w2,b} rows
    __shared__ __align__(16) f16 s_foldA[32 * 4];   // 256 B; {M0,M1,M2,v+b0b1}
    __shared__ floatx4 s_part[8][32];               // 4 KB; fold partials
    __shared__ __align__(16) float s_b0b0[32], s_fow[32];
    __shared__ __align__(16) float s_bb0f[128], s_bb1f[128];
    __shared__ float s_cam[NL][8];
    __shared__ float s_fob;

    const int tid = threadIdx.x;
    // XCD swizzle: 1D grid, b = id & 7 -> all blocks of a batch share one XCD's L2
    const int b = blockIdx.x & 7;
    const int tile = blockIdx.x >> 3;

    // ---- staging ----
    {   // s_w0A: row m = tid>>3, seg = tid&7 -> 4 b128 chunks, slot = chunk ^ (m&7)
        int m = tid >> 3, seg = tid & 7;
        const float* src = b0w0 + permrow(m) * 256 + seg * 32;
        f16* dst = s_w0A + m * 256;
        int sw = m & 7;
        #pragma unroll
        for (int ci = 0; ci < 4; ci++) {
            int cidx = seg * 4 + ci;
            floatx4 f0 = *(const floatx4*)(src + ci * 8);
            floatx4 f1 = *(const floatx4*)(src + ci * 8 + 4);
            half2v h0 = cvt2(f0[0], f0[1]), h1 = cvt2(f0[2], f0[3]);
            half2v h2 = cvt2(f1[0], f1[1]), h3 = cvt2(f1[2], f1[3]);
            half4v q0 = __builtin_shufflevector(h0, h1, 0, 1, 2, 3);
            half4v q1 = __builtin_shufflevector(h2, h3, 0, 1, 2, 3);
            half8 h = __builtin_shufflevector(q0, q1, 0, 1, 2, 3, 4, 5, 6, 7);
            *(half8*)(dst + ((cidx ^ sw) << 3)) = h;
        }
    }
    // s_wA: 9 mats x 32 rows; 4 b128 chunks per row at slot c ^ ((m>>1)&3)
    for (int r = tid; r < 288; r += 256) {
        int mi = r >> 5, m = r & 31;
        int pm = permrow(m);
        const float* src;
        if (mi == 0) src = b0w1 + pm * 32;
        else {
            int mat = mi - 1, bi = mat >> 1;
            src = ((mat & 1) ? bw1 : bw0) + (bi * 32 + pm) * 32;
        }
        f16* dst = s_wA + mi * 1024 + m * 32;
        int sw = (m >> 1) & 3;
        #pragma unroll
        for (int ci = 0; ci < 4; ci++) {
            floatx4 f0 = *(const floatx4*)(src + ci * 8);
            floatx4 f1 = *(const floatx4*)(src + ci * 8 + 4);
            half2v h0 = cvt2(f0[0], f0[1]), h1 = cvt2(f0[2], f0[3]);
            half2v h2 = cvt2(f1[0], f1[1]), h3 = cvt2(f1[2], f1[3]);
            half4v q0 = __builtin_shufflevector(h0, h1, 0, 1, 2, 3);
            half4v q1 = __builtin_shufflevector(h2, h3, 0, 1, 2, 3);
            half8 h = __builtin_shufflevector(q0, q1, 0, 1, 2, 3, 4, 5, 6, 7);
            *(half8*)(dst + ((ci ^ sw) << 3)) = h;
        }
    }
    {   // s_hB: row tid = (cch,m) holds hidden h = cch*32 + permrow(m)
        int cch = tid >> 5, m = tid & 31;
        int h = cch * 32 + permrow(m);
        half2v a = cvt2(fpw[h * 3 + 0], fpw[h * 3 + 1]);
        half2v bq = cvt2(fpw[h * 3 + 2], fpb[h]);
        *(half4v*)(s_hB + tid * 4) = __builtin_shufflevector(a, bq, 0, 1, 2, 3);
    }
    {   // fold partials: channel i = tid&31, k-slice kc = tid>>5
        int i = tid & 31, kc = tid >> 5;
        const float* wrow = b0ws + i * 256 + kc * 32;
        const float* pw = fpw + kc * 96;
        const float* pb = fpb + kc * 32;
        floatx4 acc = {};
        #pragma unroll 8
        for (int k = 0; k < 32; k++) {
            float w = wrow[k];
            acc[0] = fmaf(w, pw[k * 3 + 0], acc[0]);
            acc[1] = fmaf(w, pw[k * 3 + 1], acc[1]);
            acc[2] = fmaf(w, pw[k * 3 + 2], acc[2]);
            acc[3] = fmaf(w, pb[k], acc[3]);
        }
        s_part[kc][i] = acc;
    }
    if (tid < 32) {
        s_b0b0[tid] = b0b0[tid];
        s_fow[tid]  = fow[tid];
    }
    if (tid >= 64 && tid < 192) {
        int j = tid - 64;
        s_bb0f[j] = bb0[j];
        s_bb1f[j] = bb1[j];
    }
    if (tid == 0) s_fob = fob[0];
    if (tid >= 192 && tid < 192 + NL) {
        int l = tid - 192;
        const float* cm = Cm + ((size_t)b * NL + l) * 12;
        float denom = cm[9] + 0.05f;
        float s = 63.5f / (0.55f * denom);
        s_cam[l][0] = cm[0] * s; s_cam[l][1] = cm[1] * s; s_cam[l][2] = cm[2] * s;
        s_cam[l][3] = cm[3] * s; s_cam[l][4] = cm[4] * s; s_cam[l][5] = cm[5] * s;
    }
    __syncthreads();
    if (tid < 32) {   // fold reduce -> s_foldA (row m holds channel permrow(m))
        int pm = permrow(tid);
        floatx4 s = s_part[0][pm];
        #pragma unroll
        for (int j = 1; j < 8; j++) s += s_part[j][pm];
        half2v a = cvt2(s[0], s[1]);
        half2v bq = cvt2(s[2], s[3] + b0b1[pm]);
        *(half4v*)(s_foldA + tid * 4) = __builtin_shufflevector(a, bq, 0, 1, 2, 3);
    }
    __syncthreads();

    const int lane = tid & 63;
    const int wv = tid >> 6;
    const int q = lane >> 4;
    const int i16 = lane & 15;
    const int sw0 = i16 & 7;

    const f16* w0r0 = s_w0A + i16 * 256;
    const f16* w0r1 = s_w0A + (16 + i16) * 256;
    const int qsw = (q ^ ((i16 >> 1) & 3)) << 3;
    const int soff0 = i16 * 32 + qsw;
    const int soff1 = (16 + i16) * 32 + qsw;
    const f16* hB0 = s_hB + i16 * 4;
    const f16* hB1 = s_hB + (16 + i16) * 4;
    const float* cq = c + (((size_t)b * NL) << 19) + q * 8;
    const f16* cqh = chalf + (((size_t)b * NL) << 19) + q * 8;

    const half8 fA0 = zext4(*(const half4v*)(s_foldA + i16 * 4));
    const half8 fA1 = zext4(*(const half4v*)(s_foldA + (16 + i16) * 4));
    const floatx4 fw0 = *(const floatx4*)&s_fow[q * 8];
    const floatx4 fw1 = *(const floatx4*)&s_fow[q * 8 + 4];
    const floatx4 b00a = *(const floatx4*)&s_b0b0[q * 8];
    const floatx4 b00b = *(const floatx4*)&s_b0b0[q * 8 + 4];

    #pragma unroll 1
    for (int g = 0; g < 2; g++) {
        const int t = tile * 128 + (g * 4 + wv) * 16 + i16;
        const int tc = min(t, NT - 1);
        const float* pp = p + ((size_t)b * NT + tc) * 3;
        float px = pp[0], py = pp[1], pz = pp[2];

        // ---- bilinear multi-view gather (lane: its 8 channels) ----
        floatx4 fe0, fe1;
        if constexpr (F16) {
            half8 feh = {};
            #pragma unroll 1
            for (int l = 0; l < NL; l++) {
                float x = s_cam[l][0] * px + s_cam[l][1] * py + s_cam[l][2] * pz + 63.5f;
                float y = s_cam[l][3] * px + s_cam[l][4] * py + s_cam[l][5] * pz + 63.5f;
                int i11, i12, i21, i22; float dxw, dyw;
                corners(x, y, i11, i12, i21, i22, dxw, dyw);
                const f16* base = cqh + ((size_t)l << 19);
                half8 t11 = *(const half8*)(base + (size_t)i11 * 32);
                half8 t12 = *(const half8*)(base + (size_t)i12 * 32);
                half8 t21 = *(const half8*)(base + (size_t)i21 * 32);
                half8 t22 = *(const half8*)(base + (size_t)i22 * 32);
                float w11 = dxw * dyw;
                float w12 = (1.f - dxw) * dyw;
                float w21 = dxw * (1.f - dyw);
                float w22 = (1.f - dxw) * (1.f - dyw);
                feh += t11 * splat8(w11) + t12 * splat8(w12)
                     + t21 * splat8(w21) + t22 * splat8(w22);
            }
            fe0 = floatx4{(float)feh[0], (float)feh[1], (float)feh[2], (float)feh[3]};
            fe1 = floatx4{(float)feh[4], (float)feh[5], (float)feh[6], (float)feh[7]};
        } else {
            floatx4 a0_ = {}, a1_ = {};
            #pragma unroll 1
            for (int l = 0; l < NL; l++) {
                float x = s_cam[l][0] * px + s_cam[l][1] * py + s_cam[l][2] * pz + 63.5f;
                float y = s_cam[l][3] * px + s_cam[l][4] * py + s_cam[l][5] * pz + 63.5f;
                int i11, i12, i21, i22; float dxw, dyw;
                corners(x, y, i11, i12, i21, i22, dxw, dyw);
                const float* base = cq + ((size_t)l << 19);
                const floatx4* f11 = (const floatx4*)(base + (size_t)i11 * 32);
                const floatx4* f12 = (const floatx4*)(base + (size_t)i12 * 32);
                const floatx4* f21 = (const floatx4*)(base + (size_t)i21 * 32);
                const floatx4* f22 = (const floatx4*)(base + (size_t)i22 * 32);
                float w11 = dxw * dyw;
                float w12 = (1.f - dxw) * dyw;
                float w21 = dxw * (1.f - dyw);
                float w22 = (1.f - dxw) * (1.f - dyw);
                a0_ += f11[0] * w11 + f12[0] * w12 + f21[0] * w21 + f22[0] * w22;
                a1_ += f11[1] * w11 + f12[1] * w12 + f21[1] * w21 + f22[1] * w22;
            }
            fe0 = a0_; fe1 = a1_;
        }

        // ---- B operand for K=4 projections (rows 0..3 live on quad 0) ----
        half8 bp;
        {
            half2v xy = cvt2(px, py), z1 = cvt2(pz, 1.0f);
            half4v lo = __builtin_shufflevector(xy, z1, 0, 1, 2, 3);
            half8 full = zext4(lo);
            const half8 zh8 = {};
            bp = (q == 0) ? full : zh8;
        }

        // ---- blk0: hidden layer (via MFMA) + 256->32 ----
        floatx4 acc0 = b00a, acc1 = b00b;
        #pragma unroll 2
        for (int cch = 0; cch < 8; cch++) {
            half8 ha = zext4(*(const half4v*)(hB0 + cch * 128));
            half8 hb = zext4(*(const half4v*)(hB1 + cch * 128));
            floatx4 hz = {};
            floatx4 h0 = __builtin_amdgcn_mfma_f32_16x16x32_f16(ha, bp, hz, 0, 0, 0);
            floatx4 h1 = __builtin_amdgcn_mfma_f32_16x16x32_f16(hb, bp, hz, 0, 0, 0);
            half8 bf = relupack2(h0, h1);
            half8 a0 = *(const half8*)(w0r0 + ((((cch << 2) | q) ^ sw0) << 3));
            half8 a1 = *(const half8*)(w0r1 + ((((cch << 2) | q) ^ sw0) << 3));
            acc0 = __builtin_amdgcn_mfma_f32_16x16x32_f16(a0, bf, acc0, 0, 0, 0);
            acc1 = __builtin_amdgcn_mfma_f32_16x16x32_f16(a1, bf, acc1, 0, 0, 0);
        }

        // ---- st = fold(p)+b0b1 (MFMA, C=feat) + W1 @ relu(acc) ----
        floatx4 st0 = __builtin_amdgcn_mfma_f32_16x16x32_f16(fA0, bp, fe0, 0, 0, 0);
        floatx4 st1 = __builtin_amdgcn_mfma_f32_16x16x32_f16(fA1, bp, fe1, 0, 0, 0);
        {
            half8 bf = relupack2(acc0, acc1);
            half8 a0 = *(const half8*)(s_wA + soff0);
            half8 a1 = *(const half8*)(s_wA + soff1);
            st0 = __builtin_amdgcn_mfma_f32_16x16x32_f16(a0, bf, st0, 0, 0, 0);
            st1 = __builtin_amdgcn_mfma_f32_16x16x32_f16(a1, bf, st1, 0, 0, 0);
        }

        // ---- residual blocks ----
        #pragma unroll
        for (int bk = 0; bk < 4; bk++) {
            const f16* w_a = s_wA + (1 + 2 * bk) * 1024;
            const f16* w_b = s_wA + (2 + 2 * bk) * 1024;
            floatx4 h0 = *(const floatx4*)&s_bb0f[bk * 32 + q * 8];
            floatx4 h1 = *(const floatx4*)&s_bb0f[bk * 32 + q * 8 + 4];
            {
                half8 bf = relupack2(st0, st1);
                half8 a0 = *(const half8*)(w_a + soff0);
                half8 a1 = *(const half8*)(w_a + soff1);
                h0 = __builtin_amdgcn_mfma_f32_16x16x32_f16(a0, bf, h0, 0, 0, 0);
                h1 = __builtin_amdgcn_mfma_f32_16x16x32_f16(a1, bf, h1, 0, 0, 0);
            }
            floatx4 d0 = *(const floatx4*)&s_bb1f[bk * 32 + q * 8];
            floatx4 d1 = *(const floatx4*)&s_bb1f[bk * 32 + q * 8 + 4];
            {
                half8 bf = relupack2(h0, h1);
                half8 a0 = *(const half8*)(w_b + soff0);
                half8 a1 = *(const half8*)(w_b + soff1);
                d0 = __builtin_amdgcn_mfma_f32_16x16x32_f16(a0, bf, d0, 0, 0, 0);
                d1 = __builtin_amdgcn_mfma_f32_16x16x32_f16(a1, bf, d1, 0, 0, 0);
            }
            st0 += d0 + fe0;
            st1 += d1 + fe1;
        }

        // ---- head ----
        float o = 0.f;
        #pragma unroll
        for (int r = 0; r < 4; r++)
            o += fmaxf(st0[r], 0.f) * fw0[r] + fmaxf(st1[r], 0.f) * fw1[r];
        o += __shfl_xor(o, 16);
        o += __shfl_xor(o, 32);
        if (q == 0 && t < NT) out[(size_t)b * NT + t] = o + s_fob;
    }
}

extern "C" void kernel_launch(void* const* d_in, const int* in_sizes, int n_in,
                              void* d_out, int out_size, void* d_ws, size_t ws_size,
                              hipStream_t stream) {
    const float* p    = (const float*)d_in[0];
    const float* c    = (const float*)d_in[2];
    const float* Cm   = (const float*)d_in[3];
    const float* fpw  = (const float*)d_in[4];
    const float* fpb  = (const float*)d_in[5];
    const float* b0w0 = (const float*)d_in[6];
    const float* b0b0 = (const float*)d_in[7];
    const float* b0w1 = (const float*)d_in[8];
    const float* b0b1 = (const float*)d_in[9];
    const float* b0ws = (const float*)d_in[10];
    const float* bw0  = (const float*)d_in[11];
    const float* bb0  = (const float*)d_in[12];
    const float* bw1  = (const float*)d_in[13];
    const float* bb1  = (const float*)d_in[14];
    const float* fow  = (const float*)d_in[15];
    const float* fob  = (const float*)d_in[16];

    dim3 grid(((NT + 127) / 128) * NB);  // 1880, 1-D for XCD swizzle

    if (ws_size >= C_ELEMS * sizeof(f16)) {
        f16* chalf = (f16*)d_ws;
        convert_kernel<<<(int)(C_ELEMS / 8 / 256), 256, 0, stream>>>(c, chalf);
        decoder_kernel<true><<<grid, 256, 0, stream>>>(p, c, chalf, Cm, fpw, fpb,
                                                       b0w0, b0b0, b0w1, b0b1, b0ws,
                                                       bw0, bb0, bw1, bb1,
                                                       fow, fob, (float*)d_out);
    } else {
        decoder_kernel<false><<<grid, 256, 0, stream>>>(p, c, nullptr, Cm, fpw, fpb,
                                                        b0w0, b0b0, b0w1, b0b1, b0ws,
                                                        bw0, bb0, bw1, bb1,
                                                        fow, fob, (float*)d_out);
    }
}